// Round 8
// baseline (153.305 us; speedup 1.0000x reference)
//
#include <hip/hip_runtime.h>
#include <math.h>

#define BB 64
#define NN 512
#define FF 128
#define PADT 129   // transpose buffer pad
#define TI2 16     // matmul i-tile
#define ALSTR 520  // LDS A-row stride in bf16 elems (1040 B -> 2-way banks, free)

typedef __bf16 bf16x8 __attribute__((ext_vector_type(8)));
typedef float floatx4 __attribute__((ext_vector_type(4)));

// round-to-nearest-even f32 -> bf16 bits
__device__ __forceinline__ unsigned int bf16u(float f) {
    unsigned int u = __builtin_bit_cast(unsigned int, f);
    unsigned int r = (u + 0x7FFFu + ((u >> 16) & 1u)) >> 16;
    return r & 0xFFFFu;
}

// ---- Kernel 1: row-softmax(w) (in-block) -> A[b]=bf16(S*mask) + dvec -------
__global__ __launch_bounds__(256) void softmax_rowsum_A_kernel(
        const float* __restrict__ w, const float* __restrict__ mask,
        unsigned short* __restrict__ A, float* __restrict__ dvec) {
    __shared__ float Srow[NN];
    __shared__ float red[8];
    const int row = blockIdx.x;
    const int bg = blockIdx.y;
    const int tid = threadIdx.x;
    const int wv = tid >> 6, lane = tid & 63;

    float v0 = w[(size_t)row * NN + tid];
    float v1 = w[(size_t)row * NN + tid + 256];

    float m = fmaxf(v0, v1);
    #pragma unroll
    for (int off = 32; off > 0; off >>= 1)
        m = fmaxf(m, __shfl_down(m, off, 64));
    if (lane == 0) red[wv] = m;
    __syncthreads();
    if (tid == 0) red[4] = fmaxf(fmaxf(red[0], red[1]), fmaxf(red[2], red[3]));
    __syncthreads();
    m = red[4];

    float e0 = expf(v0 - m);
    float e1 = expf(v1 - m);
    float s = e0 + e1;
    #pragma unroll
    for (int off = 32; off > 0; off >>= 1)
        s += __shfl_down(s, off, 64);
    __syncthreads();
    if (lane == 0) red[wv] = s;
    __syncthreads();
    if (tid == 0) red[5] = 1.0f / (red[0] + red[1] + red[2] + red[3]);
    __syncthreads();
    const float inv = red[5];

    Srow[tid] = e0 * inv;
    Srow[tid + 256] = e1 * inv;
    __syncthreads();

    float4 sA = *(const float4*)&Srow[lane * 8];
    float4 sB = *(const float4*)&Srow[lane * 8 + 4];

    float4 mA[4], mB[4];
    #pragma unroll
    for (int t = 0; t < 4; ++t) {
        int b = bg * 16 + wv * 4 + t;
        const float4* mrow = (const float4*)(mask + ((size_t)b * NN + row) * NN);
        mA[t] = mrow[2 * lane];
        mB[t] = mrow[2 * lane + 1];
    }
    #pragma unroll
    for (int t = 0; t < 4; ++t) {
        int b = bg * 16 + wv * 4 + t;
        float p0 = mA[t].x * sA.x, p1 = mA[t].y * sA.y;
        float p2 = mA[t].z * sA.z, p3 = mA[t].w * sA.w;
        float p4 = mB[t].x * sB.x, p5 = mB[t].y * sB.y;
        float p6 = mB[t].z * sB.z, p7 = mB[t].w * sB.w;

        uint4 pk;
        pk.x = bf16u(p0) | (bf16u(p1) << 16);
        pk.y = bf16u(p2) | (bf16u(p3) << 16);
        pk.z = bf16u(p4) | (bf16u(p5) << 16);
        pk.w = bf16u(p6) | (bf16u(p7) << 16);
        *(uint4*)(A + ((size_t)b * NN + row) * NN + lane * 8) = pk;

        float sum = p0 + p1 + p2 + p3 + p4 + p5 + p6 + p7;
        #pragma unroll
        for (int off = 32; off > 0; off >>= 1)
            sum += __shfl_down(sum, off, 64);
        if (lane == 0) {
            float rs = sum + 1.0f;
            dvec[b * NN + row] = (rs > 0.f) ? (1.0f / sqrtf(rs)) : 0.f;
        }
    }
}

// ---- Kernel 2: Xt[b][f][j] = bf16(d_j * x[b][j][f])  (per-batch transpose) -
__global__ __launch_bounds__(256) void xt_kernel(const float* __restrict__ in,
                                                 const float* __restrict__ dvec,
                                                 unsigned short* __restrict__ Xt) {
    __shared__ unsigned short T[64 * PADT];
    const int b = blockIdx.y;
    const int j0 = blockIdx.x * 64;
    const int tid = threadIdx.x;

    const int fg = tid & 31;
    const int jr = tid >> 5;
    #pragma unroll
    for (int p = 0; p < 8; ++p) {
        int j = jr + 8 * p;
        float dj = dvec[b * NN + j0 + j];
        float4 xv = *(const float4*)(in + ((size_t)b * NN + j0 + j) * FF + 4 * fg);
        T[j * PADT + 4 * fg + 0] = (unsigned short)bf16u(xv.x * dj);
        T[j * PADT + 4 * fg + 1] = (unsigned short)bf16u(xv.y * dj);
        T[j * PADT + 4 * fg + 2] = (unsigned short)bf16u(xv.z * dj);
        T[j * PADT + 4 * fg + 3] = (unsigned short)bf16u(xv.w * dj);
    }
    __syncthreads();
    const int c = tid & 7;
    const int fr = tid >> 3;
    #pragma unroll
    for (int q = 0; q < 4; ++q) {
        int f = fr + 32 * q;
        unsigned int v01 = (unsigned int)T[(8 * c + 0) * PADT + f] |
                           ((unsigned int)T[(8 * c + 1) * PADT + f] << 16);
        unsigned int v23 = (unsigned int)T[(8 * c + 2) * PADT + f] |
                           ((unsigned int)T[(8 * c + 3) * PADT + f] << 16);
        unsigned int v45 = (unsigned int)T[(8 * c + 4) * PADT + f] |
                           ((unsigned int)T[(8 * c + 5) * PADT + f] << 16);
        unsigned int v67 = (unsigned int)T[(8 * c + 6) * PADT + f] |
                           ((unsigned int)T[(8 * c + 7) * PADT + f] << 16);
        *(uint4*)(Xt + ((size_t)b * FF + f) * NN + j0 + 8 * c) = make_uint4(v01, v23, v45, v67);
    }
}

// ---- Kernel 3: MFMA matmul — whole A-tile in LDS, ONE barrier, no dbuf -----
// block (i-tile 16 rows, batch b): A-tile = 16x512 bf16 = 16 KB, loaded in one
// coalesced burst (4x dwordx4/thread), single __syncthreads, then a
// barrier-free K-loop: Xt frag loads (L2) pipeline under unroll-4, A frags
// from LDS (stride 520 -> 2-way banks = free).
__global__ __launch_bounds__(256) void matmul_kernel(
        const unsigned short* __restrict__ A, const float* __restrict__ dvec,
        const unsigned short* __restrict__ Xt, const float* __restrict__ in,
        float* __restrict__ out) {
    __shared__ __align__(16) unsigned short Alds[TI2 * ALSTR];  // 16.6 KB

    const int b = blockIdx.y;
    const int i_base = blockIdx.x * TI2;
    const int tid = threadIdx.x;
    const int wv = tid >> 6;
    const int lane = tid & 63;
    const int q = lane >> 4;
    const int r = lane & 15;
    const int fw = wv * 32;

    // ---- stage whole A tile (contiguous 16 KB): thread t -> 4 x 16B ----
    {
        const unsigned short* atile = A + ((size_t)b * NN + i_base) * NN;
        #pragma unroll
        for (int k = 0; k < 4; ++k) {
            int e = tid * 8 + k * 2048;          // bf16 elem offset in tile
            int row = e >> 9, col = e & 511;
            *(uint4*)&Alds[row * ALSTR + col] = *(const uint4*)(atile + e);
        }
    }
    __syncthreads();   // the only barrier

    const unsigned short* xb0 = Xt + ((size_t)b * FF + fw + r) * NN + q * 8;
    const unsigned short* xb1 = xb0 + (size_t)16 * NN;

    floatx4 acc0 = (floatx4){0.f, 0.f, 0.f, 0.f};
    floatx4 acc1 = (floatx4){0.f, 0.f, 0.f, 0.f};

    #pragma unroll 4
    for (int s = 0; s < 16; ++s) {
        const int o = s * 32;
        bf16x8 b0 = *(const bf16x8*)(xb0 + o);
        bf16x8 b1 = *(const bf16x8*)(xb1 + o);
        bf16x8 af = *(const bf16x8*)&Alds[r * ALSTR + o + q * 8];
        acc0 = __builtin_amdgcn_mfma_f32_16x16x32_bf16(af, b0, acc0, 0, 0, 0);
        acc1 = __builtin_amdgcn_mfma_f32_16x16x32_bf16(af, b1, acc1, 0, 0, 0);
    }

    // epilogue: out = d_i * (acc + d_i * x_i); C/D: col=r, row=q*4+reg
    const float* dB = dvec + b * NN;
    #pragma unroll
    for (int nt = 0; nt < 2; ++nt) {
        int f = fw + nt * 16 + r;
        const floatx4& a = nt ? acc1 : acc0;
        #pragma unroll
        for (int rr = 0; rr < 4; ++rr) {
            int i = i_base + q * 4 + rr;
            float di = dB[i];
            float x = in[((size_t)b * NN + i) * FF + f];
            out[((size_t)b * NN + i) * FF + f] = di * (a[rr] + di * x);
        }
    }
}

extern "C" void kernel_launch(void* const* d_in, const int* in_sizes, int n_in,
                              void* d_out, int out_size, void* d_ws, size_t ws_size,
                              hipStream_t stream) {
    const float* inp  = (const float*)d_in[0];   // [B,N,F]
    const float* mask = (const float*)d_in[1];   // [B,N,N]
    const float* w    = (const float*)d_in[2];   // [N,N]
    float* out = (float*)d_out;                  // [B,N,F]

    unsigned short* A  = (unsigned short*)d_ws;              // [B,N,N] bf16 = 33.5 MB
    unsigned short* Xt = A + (size_t)BB * NN * NN;           // [B,F,N] bf16 = 8.4 MB
    float* dvec = (float*)(Xt + (size_t)BB * FF * NN);       // [B,N] f32

    softmax_rowsum_A_kernel<<<dim3(NN, 4), 256, 0, stream>>>(w, mask, A, dvec);
    xt_kernel<<<dim3(NN / 64, BB), 256, 0, stream>>>(inp, dvec, Xt);
    matmul_kernel<<<dim3(NN / TI2, BB), 256, 0, stream>>>(A, dvec, Xt, inp, out);
}

// Round 9
// 151.329 us; speedup vs baseline: 1.0131x; 1.0131x over previous
//
#include <hip/hip_runtime.h>
#include <math.h>

#define BB 64
#define NN 512
#define FF 128
#define PADT 129   // transpose buffer pad
#define TI2 16     // matmul i-tile
#define ALSTR 520  // LDS A-row stride in bf16 elems (1040 B -> 2-way banks, free)

typedef __bf16 bf16x8 __attribute__((ext_vector_type(8)));
typedef float floatx4 __attribute__((ext_vector_type(4)));

// round-to-nearest-even f32 -> bf16 bits
__device__ __forceinline__ unsigned int bf16u(float f) {
    unsigned int u = __builtin_bit_cast(unsigned int, f);
    unsigned int r = (u + 0x7FFFu + ((u >> 16) & 1u)) >> 16;
    return r & 0xFFFFu;
}

// ---- Kernel 1: fused row-softmax(w) -> S  AND  dvec[b,i] for 16 batches ----
// (R5 form: no A-write, 65 MB traffic)
__global__ __launch_bounds__(256) void softmax_rowsum_kernel(
        const float* __restrict__ w, const float* __restrict__ mask,
        float* __restrict__ S, float* __restrict__ dvec) {
    __shared__ float Srow[NN];
    __shared__ float red[8];
    const int row = blockIdx.x;
    const int bg = blockIdx.y;
    const int tid = threadIdx.x;
    const int wv = tid >> 6, lane = tid & 63;

    float v0 = w[(size_t)row * NN + tid];
    float v1 = w[(size_t)row * NN + tid + 256];

    float m = fmaxf(v0, v1);
    #pragma unroll
    for (int off = 32; off > 0; off >>= 1)
        m = fmaxf(m, __shfl_down(m, off, 64));
    if (lane == 0) red[wv] = m;
    __syncthreads();
    if (tid == 0) red[4] = fmaxf(fmaxf(red[0], red[1]), fmaxf(red[2], red[3]));
    __syncthreads();
    m = red[4];

    float e0 = expf(v0 - m);
    float e1 = expf(v1 - m);
    float s = e0 + e1;
    #pragma unroll
    for (int off = 32; off > 0; off >>= 1)
        s += __shfl_down(s, off, 64);
    __syncthreads();
    if (lane == 0) red[wv] = s;
    __syncthreads();
    if (tid == 0) red[5] = 1.0f / (red[0] + red[1] + red[2] + red[3]);
    __syncthreads();
    const float inv = red[5];
    const float s0v = e0 * inv, s1v = e1 * inv;

    Srow[tid] = s0v;
    Srow[tid + 256] = s1v;
    if (bg == 0) {
        S[(size_t)row * NN + tid] = s0v;
        S[(size_t)row * NN + tid + 256] = s1v;
    }
    __syncthreads();

    float4 sA = *(const float4*)&Srow[lane * 8];
    float4 sB = *(const float4*)&Srow[lane * 8 + 4];

    float4 mA[4], mB[4];
    #pragma unroll
    for (int t = 0; t < 4; ++t) {
        int b = bg * 16 + wv * 4 + t;
        const float4* mrow = (const float4*)(mask + ((size_t)b * NN + row) * NN);
        mA[t] = mrow[2 * lane];
        mB[t] = mrow[2 * lane + 1];
    }
    #pragma unroll
    for (int t = 0; t < 4; ++t) {
        float sum = mA[t].x * sA.x + mA[t].y * sA.y + mA[t].z * sA.z + mA[t].w * sA.w
                  + mB[t].x * sB.x + mB[t].y * sB.y + mB[t].z * sB.z + mB[t].w * sB.w;
        #pragma unroll
        for (int off = 32; off > 0; off >>= 1)
            sum += __shfl_down(sum, off, 64);
        if (lane == 0) {
            int b = bg * 16 + wv * 4 + t;
            float rs = sum + 1.0f;
            dvec[b * NN + row] = (rs > 0.f) ? (1.0f / sqrtf(rs)) : 0.f;
        }
    }
}

// ---- Kernel 2: Xt[b][f][j] = bf16(d_j * x[b][j][f])  (per-batch transpose) -
__global__ __launch_bounds__(256) void xt_kernel(const float* __restrict__ in,
                                                 const float* __restrict__ dvec,
                                                 unsigned short* __restrict__ Xt) {
    __shared__ unsigned short T[64 * PADT];
    const int b = blockIdx.y;
    const int j0 = blockIdx.x * 64;
    const int tid = threadIdx.x;

    const int fg = tid & 31;
    const int jr = tid >> 5;
    #pragma unroll
    for (int p = 0; p < 8; ++p) {
        int j = jr + 8 * p;
        float dj = dvec[b * NN + j0 + j];
        float4 xv = *(const float4*)(in + ((size_t)b * NN + j0 + j) * FF + 4 * fg);
        T[j * PADT + 4 * fg + 0] = (unsigned short)bf16u(xv.x * dj);
        T[j * PADT + 4 * fg + 1] = (unsigned short)bf16u(xv.y * dj);
        T[j * PADT + 4 * fg + 2] = (unsigned short)bf16u(xv.z * dj);
        T[j * PADT + 4 * fg + 3] = (unsigned short)bf16u(xv.w * dj);
    }
    __syncthreads();
    const int c = tid & 7;
    const int fr = tid >> 3;
    #pragma unroll
    for (int q = 0; q < 4; ++q) {
        int f = fr + 32 * q;
        unsigned int v01 = (unsigned int)T[(8 * c + 0) * PADT + f] |
                           ((unsigned int)T[(8 * c + 1) * PADT + f] << 16);
        unsigned int v23 = (unsigned int)T[(8 * c + 2) * PADT + f] |
                           ((unsigned int)T[(8 * c + 3) * PADT + f] << 16);
        unsigned int v45 = (unsigned int)T[(8 * c + 4) * PADT + f] |
                           ((unsigned int)T[(8 * c + 5) * PADT + f] << 16);
        unsigned int v67 = (unsigned int)T[(8 * c + 6) * PADT + f] |
                           ((unsigned int)T[(8 * c + 7) * PADT + f] << 16);
        *(uint4*)(Xt + ((size_t)b * FF + f) * NN + j0 + 8 * c) = make_uint4(v01, v23, v45, v67);
    }
}

// ---- Kernel 3: MFMA matmul — whole mask*S tile -> LDS, ONE barrier ---------
// block (16-row i-tile, batch b): stage 16x512 bf16(S*mask) into LDS in one
// coalesced fp32 burst (mask streams from HBM, S from L2/L3), single
// __syncthreads, then barrier-free K-loop vs L2-resident Xt.
__global__ __launch_bounds__(256) void matmul_kernel(
        const float* __restrict__ S, const float* __restrict__ mask,
        const float* __restrict__ dvec, const unsigned short* __restrict__ Xt,
        const float* __restrict__ in, float* __restrict__ out) {
    __shared__ __align__(16) unsigned short Alds[TI2 * ALSTR];  // 16.6 KB

    const int b = blockIdx.y;
    const int i_base = blockIdx.x * TI2;
    const int tid = threadIdx.x;
    const int wv = tid >> 6;
    const int lane = tid & 63;
    const int q = lane >> 4;
    const int r = lane & 15;
    const int fw = wv * 32;

    // ---- stage whole A tile: 16x512 elems; thread t -> 4 chunks of 8 ----
    {
        const float* mtile = mask + ((size_t)b * NN + i_base) * NN;
        const float* stile = S + (size_t)i_base * NN;
        #pragma unroll
        for (int k = 0; k < 4; ++k) {
            int e = tid * 8 + k * 2048;          // elem offset in 16x512 tile
            int row = e >> 9, col = e & 511;
            float4 m0 = *(const float4*)(mtile + (size_t)row * NN + col);
            float4 m1 = *(const float4*)(mtile + (size_t)row * NN + col + 4);
            float4 s0 = *(const float4*)(stile + (size_t)row * NN + col);
            float4 s1 = *(const float4*)(stile + (size_t)row * NN + col + 4);
            uint4 pk;
            pk.x = bf16u(m0.x * s0.x) | (bf16u(m0.y * s0.y) << 16);
            pk.y = bf16u(m0.z * s0.z) | (bf16u(m0.w * s0.w) << 16);
            pk.z = bf16u(m1.x * s1.x) | (bf16u(m1.y * s1.y) << 16);
            pk.w = bf16u(m1.z * s1.z) | (bf16u(m1.w * s1.w) << 16);
            *(uint4*)&Alds[row * ALSTR + col] = pk;
        }
    }
    __syncthreads();   // the only barrier

    const unsigned short* xb0 = Xt + ((size_t)b * FF + fw + r) * NN + q * 8;
    const unsigned short* xb1 = xb0 + (size_t)16 * NN;

    floatx4 acc0 = (floatx4){0.f, 0.f, 0.f, 0.f};
    floatx4 acc1 = (floatx4){0.f, 0.f, 0.f, 0.f};

    #pragma unroll 4
    for (int s = 0; s < 16; ++s) {
        const int o = s * 32;
        bf16x8 b0 = *(const bf16x8*)(xb0 + o);
        bf16x8 b1 = *(const bf16x8*)(xb1 + o);
        bf16x8 af = *(const bf16x8*)&Alds[r * ALSTR + o + q * 8];
        acc0 = __builtin_amdgcn_mfma_f32_16x16x32_bf16(af, b0, acc0, 0, 0, 0);
        acc1 = __builtin_amdgcn_mfma_f32_16x16x32_bf16(af, b1, acc1, 0, 0, 0);
    }

    // epilogue: out = d_i * (acc + d_i * x_i); C/D: col=r, row=q*4+reg
    const float* dB = dvec + b * NN;
    #pragma unroll
    for (int nt = 0; nt < 2; ++nt) {
        int f = fw + nt * 16 + r;
        const floatx4& a = nt ? acc1 : acc0;
        #pragma unroll
        for (int rr = 0; rr < 4; ++rr) {
            int i = i_base + q * 4 + rr;
            float di = dB[i];
            float x = in[((size_t)b * NN + i) * FF + f];
            out[((size_t)b * NN + i) * FF + f] = di * (a[rr] + di * x);
        }
    }
}

extern "C" void kernel_launch(void* const* d_in, const int* in_sizes, int n_in,
                              void* d_out, int out_size, void* d_ws, size_t ws_size,
                              hipStream_t stream) {
    const float* inp  = (const float*)d_in[0];   // [B,N,F]
    const float* mask = (const float*)d_in[1];   // [B,N,N]
    const float* w    = (const float*)d_in[2];   // [N,N]
    float* out = (float*)d_out;                  // [B,N,F]

    unsigned short* Xt = (unsigned short*)d_ws;              // [B,F,N] bf16 = 8.4 MB
    float* S    = (float*)(Xt + (size_t)BB * FF * NN);       // [N,N] f32 = 1 MB
    float* dvec = S + (size_t)NN * NN;                       // [B,N] f32

    softmax_rowsum_kernel<<<dim3(NN, 4), 256, 0, stream>>>(w, mask, S, dvec);
    xt_kernel<<<dim3(NN / 64, BB), 256, 0, stream>>>(inp, dvec, Xt);
    matmul_kernel<<<dim3(NN / TI2, BB), 256, 0, stream>>>(S, mask, dvec, Xt, inp, out);
}

// Round 10
// 149.879 us; speedup vs baseline: 1.0229x; 1.0097x over previous
//
#include <hip/hip_runtime.h>
#include <math.h>

#define BB 64
#define NN 512
#define FF 128
#define PADT 129   // transpose buffer pad
#define TI3 32     // matmul i-tile (v6)
#define ALSTR 520  // LDS A-row stride in bf16 elems (1040 B -> 2-way banks, free)

typedef __bf16 bf16x8 __attribute__((ext_vector_type(8)));
typedef float floatx4 __attribute__((ext_vector_type(4)));

// round-to-nearest-even f32 -> bf16 bits
__device__ __forceinline__ unsigned int bf16u(float f) {
    unsigned int u = __builtin_bit_cast(unsigned int, f);
    unsigned int r = (u + 0x7FFFu + ((u >> 16) & 1u)) >> 16;
    return r & 0xFFFFu;
}

// ---- Kernel 1: fused row-softmax(w) -> S  AND  dvec[b,i] for 16 batches ----
__global__ __launch_bounds__(256) void softmax_rowsum_kernel(
        const float* __restrict__ w, const float* __restrict__ mask,
        float* __restrict__ S, float* __restrict__ dvec) {
    __shared__ float Srow[NN];
    __shared__ float red[8];
    const int row = blockIdx.x;
    const int bg = blockIdx.y;
    const int tid = threadIdx.x;
    const int wv = tid >> 6, lane = tid & 63;

    float v0 = w[(size_t)row * NN + tid];
    float v1 = w[(size_t)row * NN + tid + 256];

    float m = fmaxf(v0, v1);
    #pragma unroll
    for (int off = 32; off > 0; off >>= 1)
        m = fmaxf(m, __shfl_down(m, off, 64));
    if (lane == 0) red[wv] = m;
    __syncthreads();
    if (tid == 0) red[4] = fmaxf(fmaxf(red[0], red[1]), fmaxf(red[2], red[3]));
    __syncthreads();
    m = red[4];

    float e0 = expf(v0 - m);
    float e1 = expf(v1 - m);
    float s = e0 + e1;
    #pragma unroll
    for (int off = 32; off > 0; off >>= 1)
        s += __shfl_down(s, off, 64);
    __syncthreads();
    if (lane == 0) red[wv] = s;
    __syncthreads();
    if (tid == 0) red[5] = 1.0f / (red[0] + red[1] + red[2] + red[3]);
    __syncthreads();
    const float inv = red[5];
    const float s0v = e0 * inv, s1v = e1 * inv;

    Srow[tid] = s0v;
    Srow[tid + 256] = s1v;
    if (bg == 0) {
        S[(size_t)row * NN + tid] = s0v;
        S[(size_t)row * NN + tid + 256] = s1v;
    }
    __syncthreads();

    float4 sA = *(const float4*)&Srow[lane * 8];
    float4 sB = *(const float4*)&Srow[lane * 8 + 4];

    float4 mA[4], mB[4];
    #pragma unroll
    for (int t = 0; t < 4; ++t) {
        int b = bg * 16 + wv * 4 + t;
        const float4* mrow = (const float4*)(mask + ((size_t)b * NN + row) * NN);
        mA[t] = mrow[2 * lane];
        mB[t] = mrow[2 * lane + 1];
    }
    #pragma unroll
    for (int t = 0; t < 4; ++t) {
        float sum = mA[t].x * sA.x + mA[t].y * sA.y + mA[t].z * sA.z + mA[t].w * sA.w
                  + mB[t].x * sB.x + mB[t].y * sB.y + mB[t].z * sB.z + mB[t].w * sB.w;
        #pragma unroll
        for (int off = 32; off > 0; off >>= 1)
            sum += __shfl_down(sum, off, 64);
        if (lane == 0) {
            int b = bg * 16 + wv * 4 + t;
            float rs = sum + 1.0f;
            dvec[b * NN + row] = (rs > 0.f) ? (1.0f / sqrtf(rs)) : 0.f;
        }
    }
}

// ---- Kernel 2: Xt[b][f][j] = bf16(d_j * x[b][j][f])  (per-batch transpose) -
__global__ __launch_bounds__(256) void xt_kernel(const float* __restrict__ in,
                                                 const float* __restrict__ dvec,
                                                 unsigned short* __restrict__ Xt) {
    __shared__ unsigned short T[64 * PADT];
    const int b = blockIdx.y;
    const int j0 = blockIdx.x * 64;
    const int tid = threadIdx.x;

    const int fg = tid & 31;
    const int jr = tid >> 5;
    #pragma unroll
    for (int p = 0; p < 8; ++p) {
        int j = jr + 8 * p;
        float dj = dvec[b * NN + j0 + j];
        float4 xv = *(const float4*)(in + ((size_t)b * NN + j0 + j) * FF + 4 * fg);
        T[j * PADT + 4 * fg + 0] = (unsigned short)bf16u(xv.x * dj);
        T[j * PADT + 4 * fg + 1] = (unsigned short)bf16u(xv.y * dj);
        T[j * PADT + 4 * fg + 2] = (unsigned short)bf16u(xv.z * dj);
        T[j * PADT + 4 * fg + 3] = (unsigned short)bf16u(xv.w * dj);
    }
    __syncthreads();
    const int c = tid & 7;
    const int fr = tid >> 3;
    #pragma unroll
    for (int q = 0; q < 4; ++q) {
        int f = fr + 32 * q;
        unsigned int v01 = (unsigned int)T[(8 * c + 0) * PADT + f] |
                           ((unsigned int)T[(8 * c + 1) * PADT + f] << 16);
        unsigned int v23 = (unsigned int)T[(8 * c + 2) * PADT + f] |
                           ((unsigned int)T[(8 * c + 3) * PADT + f] << 16);
        unsigned int v45 = (unsigned int)T[(8 * c + 4) * PADT + f] |
                           ((unsigned int)T[(8 * c + 5) * PADT + f] << 16);
        unsigned int v67 = (unsigned int)T[(8 * c + 6) * PADT + f] |
                           ((unsigned int)T[(8 * c + 7) * PADT + f] << 16);
        *(uint4*)(Xt + ((size_t)b * FF + f) * NN + j0 + 8 * c) = make_uint4(v01, v23, v45, v67);
    }
}

// ---- Kernel 3 (v6): 512 threads, TI=32, whole tile in LDS, one barrier -----
// grid (16,64) = 1024 blocks = exactly 4/CU; __launch_bounds__(512,8) caps
// VGPR at 64 so all 32 waves/CU are co-resident. Wave w: rows iw=(w&1)*16,
// f-slice fw=(w>>1)*32. Staging = 128 KB coalesced burst by 512 threads.
__global__ __launch_bounds__(512, 8) void matmul_kernel(
        const float* __restrict__ S, const float* __restrict__ mask,
        const float* __restrict__ dvec, const unsigned short* __restrict__ Xt,
        const float* __restrict__ in, float* __restrict__ out) {
    __shared__ __align__(16) unsigned short Alds[TI3 * ALSTR];  // 33.3 KB

    const int b = blockIdx.y;
    const int i_base = blockIdx.x * TI3;
    const int tid = threadIdx.x;
    const int w = tid >> 6;
    const int lane = tid & 63;
    const int q = lane >> 4;
    const int r = lane & 15;
    const int iw = (w & 1) * 16;
    const int fw = (w >> 1) * 32;

    // ---- stage whole 32x512 tile: thread t -> 4 chunks of 8 elems ----
    {
        const float* mtile = mask + ((size_t)b * NN + i_base) * NN;
        const float* stile = S + (size_t)i_base * NN;
        #pragma unroll
        for (int k = 0; k < 4; ++k) {
            int e = tid * 8 + k * 4096;          // elem offset in 32x512 tile
            int row = e >> 9, col = e & 511;
            float4 m0 = *(const float4*)(mtile + (size_t)row * NN + col);
            float4 m1 = *(const float4*)(mtile + (size_t)row * NN + col + 4);
            float4 s0 = *(const float4*)(stile + (size_t)row * NN + col);
            float4 s1 = *(const float4*)(stile + (size_t)row * NN + col + 4);
            uint4 pk;
            pk.x = bf16u(m0.x * s0.x) | (bf16u(m0.y * s0.y) << 16);
            pk.y = bf16u(m0.z * s0.z) | (bf16u(m0.w * s0.w) << 16);
            pk.z = bf16u(m1.x * s1.x) | (bf16u(m1.y * s1.y) << 16);
            pk.w = bf16u(m1.z * s1.z) | (bf16u(m1.w * s1.w) << 16);
            *(uint4*)&Alds[row * ALSTR + col] = pk;
        }
    }
    __syncthreads();   // the only barrier

    const unsigned short* xb0 = Xt + ((size_t)b * FF + fw + r) * NN + q * 8;
    const unsigned short* xb1 = xb0 + (size_t)16 * NN;

    floatx4 acc0 = (floatx4){0.f, 0.f, 0.f, 0.f};
    floatx4 acc1 = (floatx4){0.f, 0.f, 0.f, 0.f};

    #pragma unroll 4
    for (int s = 0; s < 16; ++s) {
        const int o = s * 32;
        bf16x8 b0 = *(const bf16x8*)(xb0 + o);
        bf16x8 b1 = *(const bf16x8*)(xb1 + o);
        bf16x8 af = *(const bf16x8*)&Alds[(iw + r) * ALSTR + o + q * 8];
        acc0 = __builtin_amdgcn_mfma_f32_16x16x32_bf16(af, b0, acc0, 0, 0, 0);
        acc1 = __builtin_amdgcn_mfma_f32_16x16x32_bf16(af, b1, acc1, 0, 0, 0);
    }

    // epilogue: out = d_i * (acc + d_i * x_i); C/D: col=r, row=q*4+reg
    const float* dB = dvec + b * NN;
    #pragma unroll
    for (int nt = 0; nt < 2; ++nt) {
        int f = fw + nt * 16 + r;
        const floatx4& a = nt ? acc1 : acc0;
        #pragma unroll
        for (int rr = 0; rr < 4; ++rr) {
            int i = i_base + iw + q * 4 + rr;
            float di = dB[i];
            float x = in[((size_t)b * NN + i) * FF + f];
            out[((size_t)b * NN + i) * FF + f] = di * (a[rr] + di * x);
        }
    }
}

extern "C" void kernel_launch(void* const* d_in, const int* in_sizes, int n_in,
                              void* d_out, int out_size, void* d_ws, size_t ws_size,
                              hipStream_t stream) {
    const float* inp  = (const float*)d_in[0];   // [B,N,F]
    const float* mask = (const float*)d_in[1];   // [B,N,N]
    const float* w    = (const float*)d_in[2];   // [N,N]
    float* out = (float*)d_out;                  // [B,N,F]

    unsigned short* Xt = (unsigned short*)d_ws;              // [B,F,N] bf16 = 8.4 MB
    float* S    = (float*)(Xt + (size_t)BB * FF * NN);       // [N,N] f32 = 1 MB
    float* dvec = S + (size_t)NN * NN;                       // [B,N] f32

    softmax_rowsum_kernel<<<dim3(NN, 4), 256, 0, stream>>>(w, mask, S, dvec);
    xt_kernel<<<dim3(NN / 64, BB), 256, 0, stream>>>(inp, dvec, Xt);
    matmul_kernel<<<dim3(NN / TI3, BB), 512, 0, stream>>>(S, mask, dvec, Xt, inp, out);
}